// Round 10
// baseline (582.948 us; speedup 1.0000x reference)
//
#include <hip/hip_runtime.h>
#include <math.h>

#define NB    512
#define FDIM  80
#define LEN   111
#define TDEC  222
#define CFDIM 32
#define EOS   113   // eoT row stride: coprime with 32 banks -> conflict-free

typedef float v2 __attribute__((ext_vector_type(2)));

__device__ __forceinline__ float rcpf(float x){ return __builtin_amdgcn_rcpf(x); }
__device__ __forceinline__ float sigm(float x){ return rcpf(1.0f + __expf(-x)); }
// tanh(x) = 1 - 2/(e^{2x}+1): valid for |x| < 40 (our args are < ~6)
__device__ __forceinline__ float ftanh(float x){
  float e = __expf(2.0f*x);
  return 1.0f - 2.0f*rcpf(e + 1.0f);
}

template<int CTRL, int ROW_MASK>
__device__ __forceinline__ float dpp_add(float x){
  int yi = __builtin_amdgcn_update_dpp(0, __builtin_bit_cast(int, x), CTRL, ROW_MASK, 0xf, false);
  return x + __builtin_bit_cast(float, yi);
}
__device__ __forceinline__ float wave_sum(float x){
  x = dpp_add<0x111, 0xf>(x);
  x = dpp_add<0x112, 0xf>(x);
  x = dpp_add<0x114, 0xf>(x);
  x = dpp_add<0x118, 0xf>(x);
  x = dpp_add<0x142, 0xa>(x);  // row_bcast:15
  x = dpp_add<0x143, 0xc>(x);  // row_bcast:31
  return __builtin_bit_cast(float, __builtin_amdgcn_readlane(__builtin_bit_cast(int, x), 63));
}
#define RL(x, u) __builtin_bit_cast(float, __builtin_amdgcn_readlane(__builtin_bit_cast(int, (x)), (u)))
#define BPERM(src, idx) __builtin_bit_cast(float, __builtin_amdgcn_ds_bpermute(((idx)&63)*4, __builtin_bit_cast(int, (src))))

__global__ __launch_bounds__(64, 1)
void attn_rnn_kernel(const float* __restrict__ g_in,
                     const float* __restrict__ enc_Wx, const float* __restrict__ enc_Wh, const float* __restrict__ enc_b,
                     const float* __restrict__ att_Wq, const float* __restrict__ att_bq,
                     const float* __restrict__ att_Wm, const float* __restrict__ att_bm,
                     const float* __restrict__ att_V,  const float* __restrict__ att_bv,
                     const float* __restrict__ loc_Wc, const float* __restrict__ loc_Wd,
                     const float* __restrict__ dec_Wx, const float* __restrict__ dec_Wh, const float* __restrict__ dec_b,
                     const float* __restrict__ out_W,  const float* __restrict__ out_b,
                     float* __restrict__ g_out)
{
  __shared__ float xp[LEN*80];
  __shared__ float eoT[20*EOS];
  __shared__ float Wm_s[200];

  const int lane = threadIdx.x;
  const int b    = blockIdx.x;
  const float* inp = g_in + (size_t)b * LEN * FDIM;

  for (int k = lane; k < 200; k += 64) Wm_s[k] = att_Wm[k];

  float V[10], wloc[10], bmv[10];
  #pragma unroll
  for (int a = 0; a < 10; a++){ V[a] = att_V[a]; bmv[a] = att_bm[a]; wloc[a] = 0.f; }
  for (int cf = 0; cf < CFDIM; ++cf){
    float lwc = loc_Wc[cf];
    #pragma unroll
    for (int a = 0; a < 10; a++) wloc[a] += lwc * loc_Wd[cf*10 + a];
  }
  const float bv = att_bv[0];
  const float ob = out_b[0];
  const float bq_l = att_bq[(lane < 10) ? lane : 0];
  const float outw = (lane < 20) ? out_W[lane] : 0.f;

  // ---- xp prologue: xp[t][j] = x[t].Wx[:,j] + b[j] ----
  {
    float wxc[80];
    #pragma unroll
    for (int i = 0; i < 80; i++) wxc[i] = enc_Wx[i*80 + lane];
    const float ebj = enc_b[lane];
    for (int t = 0; t < LEN; t++){
      const float* xr = inp + t*FDIM;
      float a0=0.f,a1=0.f,a2=0.f,a3=0.f;
      #pragma unroll
      for (int i = 0; i < 80; i += 4){
        a0 += xr[i  ]*wxc[i  ]; a1 += xr[i+1]*wxc[i+1];
        a2 += xr[i+2]*wxc[i+2]; a3 += xr[i+3]*wxc[i+3];
      }
      xp[t*80 + lane] = ebj + ((a0+a1)+(a2+a3));
    }
  }
  {
    const int col = 64 + (lane >> 2);
    float wxc[80];
    #pragma unroll
    for (int i = 0; i < 80; i++) wxc[i] = enc_Wx[i*80 + col];
    const float ebj = enc_b[col];
    for (int t = (lane & 3); t < LEN; t += 4){
      const float* xr = inp + t*FDIM;
      float a0=0.f,a1=0.f,a2=0.f,a3=0.f;
      #pragma unroll
      for (int i = 0; i < 80; i += 4){
        a0 += xr[i  ]*wxc[i  ]; a1 += xr[i+1]*wxc[i+1];
        a2 += xr[i+2]*wxc[i+2]; a3 += xr[i+3]*wxc[i+3];
      }
      xp[t*80 + col] = ebj + ((a0+a1)+(a2+a3));
    }
  }

  // second z column: cols 60..79 live in lanes 0..19 (single o-gate bpermute)
  const int c1 = 60 + ((lane < 20) ? lane : 0);
  v2 whp[20];
  #pragma unroll
  for (int u = 0; u < 20; u++)
    whp[u] = (v2){ enc_Wh[u*80 + lane], enc_Wh[u*80 + c1] };
  __syncthreads();                         // [barrier 1/2] xp + Wm_s ready

  // ================= encoder: barrier-free =================
  float s_h[20];
  #pragma unroll
  for (int u = 0; u < 20; u++) s_h[u] = 0.f;
  float c_enc = 0.f;
  for (int t = 0; t < LEN; t++){
    v2 acc = (v2){ xp[t*80 + lane], xp[t*80 + c1] };
    #pragma unroll
    for (int u = 0; u < 20; u++) acc += s_h[u]*whp[u];   // v_pk_fma
    float a0 = acc.x, a1 = acc.y;          // z[lane], z[60+lane] (lanes<20)
    float zf = BPERM(a0, lane+20);
    float zg = BPERM(a0, lane+40);
    float zo = BPERM(a1, lane);            // z[60+u] for u<20
    float hval = 0.f;
    if (lane < 20){
      c_enc = sigm(zf)*c_enc + sigm(a0)*ftanh(zg);
      hval  = sigm(zo)*ftanh(c_enc);
      eoT[lane*EOS + t] = hval;
    }
    #pragma unroll
    for (int u = 0; u < 20; u++) s_h[u] = RL(hval, u);
  }
  __syncthreads();                         // [barrier 2/2] eoT ready

  // ---- per-lane eo rows + mem_proj rows -> registers ----
  const int l1 = (lane < 47) ? lane + 64 : lane;
  float er0[20], er1[20];
  #pragma unroll
  for (int u = 0; u < 20; u++){ er0[u] = eoT[u*EOS + lane]; er1[u] = eoT[u*EOS + l1]; }
  float mp0[10], mp1[10];
  #pragma unroll
  for (int a = 0; a < 10; a++){
    float m0 = bmv[a], m1 = bmv[a];
    #pragma unroll
    for (int u = 0; u < 20; u++){ m0 += er0[u]*Wm_s[u*10 + a]; m1 += er1[u]*Wm_s[u*10 + a]; }
    mp0[a] = m0; mp1[a] = m1;
  }

  // ---- decoder weights (packed pairs for z) ----
  v2 dwxp[20], dwhp[20];
  #pragma unroll
  for (int u = 0; u < 20; u++){
    dwxp[u] = (v2){ dec_Wx[u*80 + lane], dec_Wx[u*80 + c1] };
    dwhp[u] = (v2){ dec_Wh[u*80 + lane], dec_Wh[u*80 + c1] };
  }
  const v2 dbp = (v2){ dec_b[lane], dec_b[c1] };
  float wq[20];
  if (lane < 10){
    #pragma unroll
    for (int u = 0; u < 20; u++) wq[u] = att_Wq[u*10 + lane];
  }

  float s_c[20];
  #pragma unroll
  for (int u = 0; u < 20; u++){ s_c[u] = 0.f; s_h[u] = 0.f; }

  // ================= decoder: barrier-free, zero LDS traffic =================
  float ap0, ap1, c_dec = 0.f;
  float lt0[10], lt1[10];                  // tanh(wloc*ap) pipelined from prev step
  #pragma unroll
  for (int a = 0; a < 10; a++){ lt0[a] = 0.f; lt1[a] = 0.f; }  // ap(0)=0 -> tanh=0

  for (int t = 0; t < TDEC; t++){
    // q = c @ att_Wq + bq (query from CELL state, per reference)
    float qv = bq_l;
    if (lane < 10){
      float qa = 0.f, qb = 0.f;
      #pragma unroll
      for (int u = 0; u < 20; u += 2){ qa += s_c[u]*wq[u]; qb += s_c[u+1]*wq[u+1]; }
      qv += qa + qb;
    }
    float s_q[10];
    #pragma unroll
    for (int a = 0; a < 10; a++) s_q[a] = RL(qv, a);

    // scores with precomputed loc-tanh
    float sa0 = bv, sb0 = 0.f, sa1 = bv, sb1 = 0.f;
    #pragma unroll
    for (int a = 0; a < 10; a += 2){
      float pre0 = mp0[a]   + s_q[a]   + lt0[a];
      float pre1 = mp1[a]   + s_q[a]   + lt1[a];
      float pr20 = mp0[a+1] + s_q[a+1] + lt0[a+1];
      float pr21 = mp1[a+1] + s_q[a+1] + lt1[a+1];
      sa0 += ftanh(pre0)*V[a];   sa1 += ftanh(pre1)*V[a];
      sb0 += ftanh(pr20)*V[a+1]; sb1 += ftanh(pr21)*V[a+1];
    }
    // |sc| <= |bv|+sum|V| (~2): exp cannot overflow -> no max subtraction
    float e0 = __expf(sa0 + sb0);
    float e1 = (lane < 47) ? __expf(sa1 + sb1) : 0.f;
    float inv = rcpf(wave_sum(e0 + e1));
    ap0 = e0*inv; ap1 = e1*inv;

    // NEXT step's loc-tanh: independent of everything below -> interleaves
    #pragma unroll
    for (int a = 0; a < 10; a++){ lt0[a] = ftanh(wloc[a]*ap0); lt1[a] = ftanh(wloc[a]*ap1); }

    // z h-part first (independent of ctx)
    v2 zh = dbp;
    #pragma unroll
    for (int u = 0; u < 20; u++) zh += s_h[u]*dwhp[u];

    // ctx raw reduces (inv factored out of the 20 muls)
    float ws[20];
    #pragma unroll
    for (int u = 0; u < 20; u++) ws[u] = wave_sum(e0*er0[u] + e1*er1[u]);

    v2 zx = (v2){0.f, 0.f};
    #pragma unroll
    for (int u = 0; u < 20; u++) zx += ws[u]*dwxp[u];

    float a0 = zh.x + zx.x*inv;
    float a1 = zh.y + zx.y*inv;
    float zf = BPERM(a0, lane+20);
    float zg = BPERM(a0, lane+40);
    float zo = BPERM(a1, lane);

    float hval = 0.f;
    if (lane < 20){
      c_dec = sigm(zf)*c_dec + sigm(a0)*ftanh(zg);
      hval  = sigm(zo)*ftanh(c_dec);
    }

    // state broadcast FIRST (critical path to next q/z)
    #pragma unroll
    for (int u = 0; u < 20; u++){ s_c[u] = RL(c_dec, u); s_h[u] = RL(hval, u); }

    // y output last (dead-end, drains under next step's issue)
    float pv = wave_sum(hval*outw);
    if (lane == 0) g_out[(size_t)b*TDEC + t] = ftanh(pv + ob);
  }
}

extern "C" void kernel_launch(void* const* d_in, const int* in_sizes, int n_in,
                              void* d_out, int out_size, void* d_ws, size_t ws_size,
                              hipStream_t stream) {
  const float* g_in   = (const float*)d_in[0];
  const float* enc_Wx = (const float*)d_in[1];
  const float* enc_Wh = (const float*)d_in[2];
  const float* enc_b  = (const float*)d_in[3];
  const float* att_Wq = (const float*)d_in[4];
  const float* att_bq = (const float*)d_in[5];
  const float* att_Wm = (const float*)d_in[6];
  const float* att_bm = (const float*)d_in[7];
  const float* att_V  = (const float*)d_in[8];
  const float* att_bv = (const float*)d_in[9];
  const float* loc_Wc = (const float*)d_in[10];
  const float* loc_Wd = (const float*)d_in[11];
  const float* dec_Wx = (const float*)d_in[12];
  const float* dec_Wh = (const float*)d_in[13];
  const float* dec_b  = (const float*)d_in[14];
  const float* out_W  = (const float*)d_in[15];
  const float* out_b  = (const float*)d_in[16];
  float* g_out = (float*)d_out;

  hipLaunchKernelGGL(attn_rnn_kernel, dim3(NB), dim3(64), 0, stream,
                     g_in, enc_Wx, enc_Wh, enc_b, att_Wq, att_bq, att_Wm, att_bm,
                     att_V, att_bv, loc_Wc, loc_Wd, dec_Wx, dec_Wh, dec_b,
                     out_W, out_b, g_out);
}

// Round 11
// 576.298 us; speedup vs baseline: 1.0115x; 1.0115x over previous
//
#include <hip/hip_runtime.h>
#include <math.h>

#define NB    512
#define FDIM  80
#define LEN   111
#define TDEC  222
#define CFDIM 32
#define EOS   113   // eoT row stride: coprime with 32 banks -> conflict-free

typedef float v2 __attribute__((ext_vector_type(2)));

__device__ __forceinline__ float rcpf(float x){ return __builtin_amdgcn_rcpf(x); }
__device__ __forceinline__ float sigm(float x){ return rcpf(1.0f + __expf(-x)); }
// tanh(x) = 1 - 2/(e^{2x}+1): valid for |x| < 40 (our args are < ~6)
__device__ __forceinline__ float ftanh(float x){
  float e = __expf(2.0f*x);
  return 1.0f - 2.0f*rcpf(e + 1.0f);
}

template<int CTRL, int ROW_MASK>
__device__ __forceinline__ float dpp_add(float x){
  int yi = __builtin_amdgcn_update_dpp(0, __builtin_bit_cast(int, x), CTRL, ROW_MASK, 0xf, false);
  return x + __builtin_bit_cast(float, yi);
}
__device__ __forceinline__ float wave_sum(float x){
  x = dpp_add<0x111, 0xf>(x);
  x = dpp_add<0x112, 0xf>(x);
  x = dpp_add<0x114, 0xf>(x);
  x = dpp_add<0x118, 0xf>(x);
  x = dpp_add<0x142, 0xa>(x);  // row_bcast:15
  x = dpp_add<0x143, 0xc>(x);  // row_bcast:31
  return __builtin_bit_cast(float, __builtin_amdgcn_readlane(__builtin_bit_cast(int, x), 63));
}
#define RL(x, u) __builtin_bit_cast(float, __builtin_amdgcn_readlane(__builtin_bit_cast(int, (x)), (u)))
#define BPERM(src, idx) __builtin_bit_cast(float, __builtin_amdgcn_ds_bpermute(((idx)&63)*4, __builtin_bit_cast(int, (src))))

__global__ __launch_bounds__(64, 1)
void attn_rnn_kernel(const float* __restrict__ g_in,
                     const float* __restrict__ enc_Wx, const float* __restrict__ enc_Wh, const float* __restrict__ enc_b,
                     const float* __restrict__ att_Wq, const float* __restrict__ att_bq,
                     const float* __restrict__ att_Wm, const float* __restrict__ att_bm,
                     const float* __restrict__ att_V,  const float* __restrict__ att_bv,
                     const float* __restrict__ loc_Wc, const float* __restrict__ loc_Wd,
                     const float* __restrict__ dec_Wx, const float* __restrict__ dec_Wh, const float* __restrict__ dec_b,
                     const float* __restrict__ out_W,  const float* __restrict__ out_b,
                     float* __restrict__ g_out)
{
  __shared__ float xp[LEN*80];
  __shared__ float eoT[20*EOS];
  __shared__ float Wm_s[200];

  const int lane = threadIdx.x;
  const int b    = blockIdx.x;
  const float* inp = g_in + (size_t)b * LEN * FDIM;

  for (int k = lane; k < 200; k += 64) Wm_s[k] = att_Wm[k];

  float V[10], wloc[10], bmv[10];
  #pragma unroll
  for (int a = 0; a < 10; a++){ V[a] = att_V[a]; bmv[a] = att_bm[a]; wloc[a] = 0.f; }
  for (int cf = 0; cf < CFDIM; ++cf){
    float lwc = loc_Wc[cf];
    #pragma unroll
    for (int a = 0; a < 10; a++) wloc[a] += lwc * loc_Wd[cf*10 + a];
  }
  const float bv = att_bv[0];
  const float ob = out_b[0];
  const float bq_l = att_bq[(lane < 10) ? lane : 0];
  const float outw = (lane < 20) ? out_W[lane] : 0.f;

  // ---- xp prologue: xp[t][j] = x[t].Wx[:,j] + b[j] ----
  {
    float wxc[80];
    #pragma unroll
    for (int i = 0; i < 80; i++) wxc[i] = enc_Wx[i*80 + lane];
    const float ebj = enc_b[lane];
    for (int t = 0; t < LEN; t++){
      const float* xr = inp + t*FDIM;
      float a0=0.f,a1=0.f,a2=0.f,a3=0.f;
      #pragma unroll
      for (int i = 0; i < 80; i += 4){
        a0 += xr[i  ]*wxc[i  ]; a1 += xr[i+1]*wxc[i+1];
        a2 += xr[i+2]*wxc[i+2]; a3 += xr[i+3]*wxc[i+3];
      }
      xp[t*80 + lane] = ebj + ((a0+a1)+(a2+a3));
    }
  }
  {
    const int col = 64 + (lane >> 2);
    float wxc[80];
    #pragma unroll
    for (int i = 0; i < 80; i++) wxc[i] = enc_Wx[i*80 + col];
    const float ebj = enc_b[col];
    for (int t = (lane & 3); t < LEN; t += 4){
      const float* xr = inp + t*FDIM;
      float a0=0.f,a1=0.f,a2=0.f,a3=0.f;
      #pragma unroll
      for (int i = 0; i < 80; i += 4){
        a0 += xr[i  ]*wxc[i  ]; a1 += xr[i+1]*wxc[i+1];
        a2 += xr[i+2]*wxc[i+2]; a3 += xr[i+3]*wxc[i+3];
      }
      xp[t*80 + col] = ebj + ((a0+a1)+(a2+a3));
    }
  }

  // second z column: cols 60..79 live in lanes 0..19 (single o-gate bpermute)
  const int c1 = 60 + ((lane < 20) ? lane : 0);
  v2 whp[20];
  #pragma unroll
  for (int u = 0; u < 20; u++)
    whp[u] = (v2){ enc_Wh[u*80 + lane], enc_Wh[u*80 + c1] };
  __syncthreads();                         // [barrier 1/2] xp + Wm_s ready

  // ================= encoder: barrier-free =================
  float s_h[20];
  #pragma unroll
  for (int u = 0; u < 20; u++) s_h[u] = 0.f;
  float c_enc = 0.f;
  for (int t = 0; t < LEN; t++){
    v2 acc = (v2){ xp[t*80 + lane], xp[t*80 + c1] };
    #pragma unroll
    for (int u = 0; u < 20; u++) acc += s_h[u]*whp[u];   // v_pk_fma
    float a0 = acc.x, a1 = acc.y;          // z[lane], z[60+lane] (lanes<20)
    float zf = BPERM(a0, lane+20);
    float zg = BPERM(a0, lane+40);
    float zo = BPERM(a1, lane);            // z[60+u] for u<20
    float hval = 0.f;
    if (lane < 20){
      c_enc = sigm(zf)*c_enc + sigm(a0)*ftanh(zg);
      hval  = sigm(zo)*ftanh(c_enc);
      eoT[lane*EOS + t] = hval;
    }
    #pragma unroll
    for (int u = 0; u < 20; u++) s_h[u] = RL(hval, u);
  }
  __syncthreads();                         // [barrier 2/2] eoT ready

  // ---- per-lane eo rows + mem_proj rows -> registers ----
  const int l1 = (lane < 47) ? lane + 64 : lane;
  float er0[20], er1[20];
  #pragma unroll
  for (int u = 0; u < 20; u++){ er0[u] = eoT[u*EOS + lane]; er1[u] = eoT[u*EOS + l1]; }
  float mp0[10], mp1[10];
  #pragma unroll
  for (int a = 0; a < 10; a++){
    float m0 = bmv[a], m1 = bmv[a];
    #pragma unroll
    for (int u = 0; u < 20; u++){ m0 += er0[u]*Wm_s[u*10 + a]; m1 += er1[u]*Wm_s[u*10 + a]; }
    mp0[a] = m0; mp1[a] = m1;
  }

  // ---- decoder weights (packed pairs for z) ----
  v2 dwxp[20], dwhp[20];
  #pragma unroll
  for (int u = 0; u < 20; u++){
    dwxp[u] = (v2){ dec_Wx[u*80 + lane], dec_Wx[u*80 + c1] };
    dwhp[u] = (v2){ dec_Wh[u*80 + lane], dec_Wh[u*80 + c1] };
  }
  const v2 dbp = (v2){ dec_b[lane], dec_b[c1] };
  float wq[20];
  if (lane < 10){
    #pragma unroll
    for (int u = 0; u < 20; u++) wq[u] = att_Wq[u*10 + lane];
  }

  float s_c[20];
  #pragma unroll
  for (int u = 0; u < 20; u++){ s_c[u] = 0.f; s_h[u] = 0.f; }

  // ================= decoder: rotated loop =================
  // Tail of step t primes step t+1: q, s_q, loc-tanh, zh. Prime t=0 here:
  float c_dec = 0.f;
  float s_q[10];
  {
    float qv = bq_l;                       // c=0 -> q = bq
    #pragma unroll
    for (int a = 0; a < 10; a++) s_q[a] = RL(qv, a);
  }
  float lt0[10], lt1[10];                  // tanh(wloc*ap_prev); ap(0)=0
  #pragma unroll
  for (int a = 0; a < 10; a++){ lt0[a] = 0.f; lt1[a] = 0.f; }
  v2 zh = dbp;                             // h=0 -> zh = dec_b

  for (int t = 0; t < TDEC; t++){
    // ---------- critical region ----------
    // scores (mp, s_q, lt all ready in registers)
    float sa0 = bv, sb0 = 0.f, sa1 = bv, sb1 = 0.f;
    #pragma unroll
    for (int a = 0; a < 10; a += 2){
      float pre0 = mp0[a]   + s_q[a]   + lt0[a];
      float pre1 = mp1[a]   + s_q[a]   + lt1[a];
      float pr20 = mp0[a+1] + s_q[a+1] + lt0[a+1];
      float pr21 = mp1[a+1] + s_q[a+1] + lt1[a+1];
      sa0 += ftanh(pre0)*V[a];   sa1 += ftanh(pre1)*V[a];
      sb0 += ftanh(pr20)*V[a+1]; sb1 += ftanh(pr21)*V[a+1];
    }
    // |sc| <= |bv|+sum|V| (~2): exp cannot overflow -> no max subtraction
    float e0 = __expf(sa0 + sb0);
    float e1 = (lane < 47) ? __expf(sa1 + sb1) : 0.f;
    float inv = rcpf(wave_sum(e0 + e1));

    // ctx raw reduces (20 independent DPP trees)
    float ws[20];
    #pragma unroll
    for (int u = 0; u < 20; u++) ws[u] = wave_sum(e0*er0[u] + e1*er1[u]);

    v2 zx = (v2){0.f, 0.f};
    #pragma unroll
    for (int u = 0; u < 20; u++) zx += ws[u]*dwxp[u];

    float a0 = zh.x + zx.x*inv;
    float a1 = zh.y + zx.y*inv;
    float zf = BPERM(a0, lane+20);
    float zg = BPERM(a0, lane+40);
    float zo = BPERM(a1, lane);

    float hval = 0.f;
    if (lane < 20){
      c_dec = sigm(zf)*c_dec + sigm(a0)*ftanh(zg);
      hval  = sigm(zo)*ftanh(c_dec);
    }
    // state broadcast (feeds next step's q and zh)
    #pragma unroll
    for (int u = 0; u < 20; u++){ s_c[u] = RL(c_dec, u); s_h[u] = RL(hval, u); }

    // ---------- tail: primes step t+1, all off the critical region ----------
    float ap0 = e0*inv, ap1 = e1*inv;
    // q(t+1) from new c
    float qv = bq_l;
    if (lane < 10){
      float qa = 0.f, qb = 0.f;
      #pragma unroll
      for (int u = 0; u < 20; u += 2){ qa += s_c[u]*wq[u]; qb += s_c[u+1]*wq[u+1]; }
      qv += qa + qb;
    }
    #pragma unroll
    for (int a = 0; a < 10; a++) s_q[a] = RL(qv, a);
    // loc-tanh(t+1) from ap(t)
    #pragma unroll
    for (int a = 0; a < 10; a++){ lt0[a] = ftanh(wloc[a]*ap0); lt1[a] = ftanh(wloc[a]*ap1); }
    // zh(t+1) from new h
    zh = dbp;
    #pragma unroll
    for (int u = 0; u < 20; u++) zh += s_h[u]*dwhp[u];
    // y output (dead-end)
    float pv = wave_sum(hval*outw);
    if (lane == 0) g_out[(size_t)b*TDEC + t] = ftanh(pv + ob);
  }
}

extern "C" void kernel_launch(void* const* d_in, const int* in_sizes, int n_in,
                              void* d_out, int out_size, void* d_ws, size_t ws_size,
                              hipStream_t stream) {
  const float* g_in   = (const float*)d_in[0];
  const float* enc_Wx = (const float*)d_in[1];
  const float* enc_Wh = (const float*)d_in[2];
  const float* enc_b  = (const float*)d_in[3];
  const float* att_Wq = (const float*)d_in[4];
  const float* att_bq = (const float*)d_in[5];
  const float* att_Wm = (const float*)d_in[6];
  const float* att_bm = (const float*)d_in[7];
  const float* att_V  = (const float*)d_in[8];
  const float* att_bv = (const float*)d_in[9];
  const float* loc_Wc = (const float*)d_in[10];
  const float* loc_Wd = (const float*)d_in[11];
  const float* dec_Wx = (const float*)d_in[12];
  const float* dec_Wh = (const float*)d_in[13];
  const float* dec_b  = (const float*)d_in[14];
  const float* out_W  = (const float*)d_in[15];
  const float* out_b  = (const float*)d_in[16];
  float* g_out = (float*)d_out;

  hipLaunchKernelGGL(attn_rnn_kernel, dim3(NB), dim3(64), 0, stream,
                     g_in, enc_Wx, enc_Wh, enc_b, att_Wq, att_bq, att_Wm, att_bm,
                     att_V, att_bv, loc_Wc, loc_Wd, dec_Wx, dec_Wh, dec_b,
                     out_W, out_b, g_out);
}

// Round 12
// 570.061 us; speedup vs baseline: 1.0226x; 1.0109x over previous
//
#include <hip/hip_runtime.h>
#include <math.h>

#define NB    512
#define FDIM  80
#define LEN   111
#define TDEC  222
#define CFDIM 32
#define EOS   113   // eoT row stride: coprime with 32 banks -> conflict-free

typedef float v2 __attribute__((ext_vector_type(2)));

__device__ __forceinline__ float rcpf(float x){ return __builtin_amdgcn_rcpf(x); }
__device__ __forceinline__ float sigm(float x){ return rcpf(1.0f + __expf(-x)); }
// tanh(x) = 1 - 2/(e^{2x}+1): valid for |x| < 40 (our args are < ~6)
__device__ __forceinline__ float ftanh(float x){
  float e = __expf(2.0f*x);
  return 1.0f - 2.0f*rcpf(e + 1.0f);
}

template<int CTRL, int ROW_MASK>
__device__ __forceinline__ float dpp_add(float x){
  int yi = __builtin_amdgcn_update_dpp(0, __builtin_bit_cast(int, x), CTRL, ROW_MASK, 0xf, false);
  return x + __builtin_bit_cast(float, yi);
}
__device__ __forceinline__ float wave_sum(float x){
  x = dpp_add<0x111, 0xf>(x);
  x = dpp_add<0x112, 0xf>(x);
  x = dpp_add<0x114, 0xf>(x);
  x = dpp_add<0x118, 0xf>(x);
  x = dpp_add<0x142, 0xa>(x);  // row_bcast:15
  x = dpp_add<0x143, 0xc>(x);  // row_bcast:31
  return __builtin_bit_cast(float, __builtin_amdgcn_readlane(__builtin_bit_cast(int, x), 63));
}
#define RL(x, u) __builtin_bit_cast(float, __builtin_amdgcn_readlane(__builtin_bit_cast(int, (x)), (u)))
#define BPERM(src, idx) __builtin_bit_cast(float, __builtin_amdgcn_ds_bpermute(((idx)&63)*4, __builtin_bit_cast(int, (src))))

__global__ __launch_bounds__(64, 1)
void attn_rnn_kernel(const float* __restrict__ g_in,
                     const float* __restrict__ enc_Wx, const float* __restrict__ enc_Wh, const float* __restrict__ enc_b,
                     const float* __restrict__ att_Wq, const float* __restrict__ att_bq,
                     const float* __restrict__ att_Wm, const float* __restrict__ att_bm,
                     const float* __restrict__ att_V,  const float* __restrict__ att_bv,
                     const float* __restrict__ loc_Wc, const float* __restrict__ loc_Wd,
                     const float* __restrict__ dec_Wx, const float* __restrict__ dec_Wh, const float* __restrict__ dec_b,
                     const float* __restrict__ out_W,  const float* __restrict__ out_b,
                     float* __restrict__ g_out)
{
  __shared__ float xp[LEN*80];
  __shared__ float eoT[20*EOS];
  __shared__ float Wm_s[200];

  const int lane = threadIdx.x;
  const int b    = blockIdx.x;
  const float* inp = g_in + (size_t)b * LEN * FDIM;

  for (int k = lane; k < 200; k += 64) Wm_s[k] = att_Wm[k];

  float V[10], wloc[10], bmv[10];
  #pragma unroll
  for (int a = 0; a < 10; a++){ V[a] = att_V[a]; bmv[a] = att_bm[a]; wloc[a] = 0.f; }
  for (int cf = 0; cf < CFDIM; ++cf){
    float lwc = loc_Wc[cf];
    #pragma unroll
    for (int a = 0; a < 10; a++) wloc[a] += lwc * loc_Wd[cf*10 + a];
  }
  const float bv = att_bv[0];
  const float ob = out_b[0];
  const float bq_l = att_bq[(lane < 10) ? lane : 0];
  const float outw = (lane < 20) ? out_W[lane] : 0.f;
  // scores fold: sum_a V_a*tanh(pre_a) = SV - 2*sum_a V_a*rcp(e^{2pre_a}+1)
  float SB = bv;
  #pragma unroll
  for (int a = 0; a < 10; a++) SB += V[a];

  // ---- xp prologue: xp[t][j] = x[t].Wx[:,j] + b[j] ----
  {
    float wxc[80];
    #pragma unroll
    for (int i = 0; i < 80; i++) wxc[i] = enc_Wx[i*80 + lane];
    const float ebj = enc_b[lane];
    for (int t = 0; t < LEN; t++){
      const float* xr = inp + t*FDIM;
      float a0=0.f,a1=0.f,a2=0.f,a3=0.f;
      #pragma unroll
      for (int i = 0; i < 80; i += 4){
        a0 += xr[i  ]*wxc[i  ]; a1 += xr[i+1]*wxc[i+1];
        a2 += xr[i+2]*wxc[i+2]; a3 += xr[i+3]*wxc[i+3];
      }
      xp[t*80 + lane] = ebj + ((a0+a1)+(a2+a3));
    }
  }
  {
    const int col = 64 + (lane >> 2);
    float wxc[80];
    #pragma unroll
    for (int i = 0; i < 80; i++) wxc[i] = enc_Wx[i*80 + col];
    const float ebj = enc_b[col];
    for (int t = (lane & 3); t < LEN; t += 4){
      const float* xr = inp + t*FDIM;
      float a0=0.f,a1=0.f,a2=0.f,a3=0.f;
      #pragma unroll
      for (int i = 0; i < 80; i += 4){
        a0 += xr[i  ]*wxc[i  ]; a1 += xr[i+1]*wxc[i+1];
        a2 += xr[i+2]*wxc[i+2]; a3 += xr[i+3]*wxc[i+3];
      }
      xp[t*80 + col] = ebj + ((a0+a1)+(a2+a3));
    }
  }

  // second z column: cols 60..79 live in lanes 0..19 -> o-gate is LANE-LOCAL
  const int c1 = 60 + ((lane < 20) ? lane : 0);
  v2 whp[20];
  #pragma unroll
  for (int u = 0; u < 20; u++)
    whp[u] = (v2){ enc_Wh[u*80 + lane], enc_Wh[u*80 + c1] };
  __syncthreads();                         // [barrier 1/2] xp + Wm_s ready

  // ================= encoder: barrier-free =================
  float s_h[20];
  #pragma unroll
  for (int u = 0; u < 20; u++) s_h[u] = 0.f;
  float c_enc = 0.f;
  for (int t = 0; t < LEN; t++){
    // 4-way split accumulator chains (5-deep each)
    v2 ac0 = (v2){ xp[t*80 + lane], xp[t*80 + c1] };
    v2 ac1 = (v2){0.f,0.f}, ac2 = (v2){0.f,0.f}, ac3 = (v2){0.f,0.f};
    #pragma unroll
    for (int u = 0; u < 20; u += 4){
      ac0 += s_h[u  ]*whp[u  ];
      ac1 += s_h[u+1]*whp[u+1];
      ac2 += s_h[u+2]*whp[u+2];
      ac3 += s_h[u+3]*whp[u+3];
    }
    v2 acc = (ac0 + ac1) + (ac2 + ac3);
    float a0 = acc.x, a1 = acc.y;          // z[lane], z[60+lane] (lanes<20)
    float zf = BPERM(a0, lane+20);
    float zg = BPERM(a0, lane+40);
    // zo = a1: lane-local, no permute needed
    float hval = 0.f;
    if (lane < 20){
      c_enc = sigm(zf)*c_enc + sigm(a0)*ftanh(zg);
      hval  = sigm(a1)*ftanh(c_enc);
      eoT[lane*EOS + t] = hval;
    }
    #pragma unroll
    for (int u = 0; u < 20; u++) s_h[u] = RL(hval, u);
  }
  __syncthreads();                         // [barrier 2/2] eoT ready

  // ---- per-lane eo rows + mem_proj rows -> registers ----
  const int l1 = (lane < 47) ? lane + 64 : lane;
  float er0[20], er1[20];
  #pragma unroll
  for (int u = 0; u < 20; u++){ er0[u] = eoT[u*EOS + lane]; er1[u] = eoT[u*EOS + l1]; }
  float mp0[10], mp1[10];
  #pragma unroll
  for (int a = 0; a < 10; a++){
    float m0 = bmv[a], m1 = bmv[a];
    #pragma unroll
    for (int u = 0; u < 20; u++){ m0 += er0[u]*Wm_s[u*10 + a]; m1 += er1[u]*Wm_s[u*10 + a]; }
    mp0[a] = m0; mp1[a] = m1;
  }

  // ---- decoder weights (packed pairs for z) ----
  v2 dwxp[20], dwhp[20];
  #pragma unroll
  for (int u = 0; u < 20; u++){
    dwxp[u] = (v2){ dec_Wx[u*80 + lane], dec_Wx[u*80 + c1] };
    dwhp[u] = (v2){ dec_Wh[u*80 + lane], dec_Wh[u*80 + c1] };
  }
  const v2 dbp = (v2){ dec_b[lane], dec_b[c1] };
  float wq[20];
  if (lane < 10){
    #pragma unroll
    for (int u = 0; u < 20; u++) wq[u] = att_Wq[u*10 + lane];
  }

  float s_c[20];
  #pragma unroll
  for (int u = 0; u < 20; u++){ s_c[u] = 0.f; s_h[u] = 0.f; }

  // ================= decoder: r9 order, shortened chains =================
  float ap0 = 0.f, ap1 = 0.f, c_dec = 0.f;
  for (int t = 0; t < TDEC; t++){
    // q = c @ att_Wq + bq (query from CELL state, per reference)
    float qv = bq_l;
    if (lane < 10){
      float qa = 0.f, qb = 0.f;
      #pragma unroll
      for (int u = 0; u < 20; u += 2){ qa += s_c[u]*wq[u]; qb += s_c[u+1]*wq[u+1]; }
      qv += qa + qb;
    }
    float s_q[10];
    #pragma unroll
    for (int a = 0; a < 10; a++) s_q[a] = RL(qv, a);

    // scores: sc = SB - 2*sum_a V_a * rcp(exp(2*pre_a)+1)   (inline loc-tanh)
    float r00 = 0.f, r01 = 0.f, r10 = 0.f, r11 = 0.f;
    #pragma unroll
    for (int a = 0; a < 10; a += 2){
      float pre0 = mp0[a]   + s_q[a]   + ftanh(wloc[a]*ap0);
      float pre1 = mp1[a]   + s_q[a]   + ftanh(wloc[a]*ap1);
      float pr20 = mp0[a+1] + s_q[a+1] + ftanh(wloc[a+1]*ap0);
      float pr21 = mp1[a+1] + s_q[a+1] + ftanh(wloc[a+1]*ap1);
      r00 += V[a]  *rcpf(__expf(2.0f*pre0) + 1.0f);
      r01 += V[a]  *rcpf(__expf(2.0f*pre1) + 1.0f);
      r10 += V[a+1]*rcpf(__expf(2.0f*pr20) + 1.0f);
      r11 += V[a+1]*rcpf(__expf(2.0f*pr21) + 1.0f);
    }
    // |sc| <= |bv|+sum|V| (~2): exp cannot overflow -> no max subtraction
    float e0 = __expf(SB - 2.0f*(r00 + r10));
    float e1 = (lane < 47) ? __expf(SB - 2.0f*(r01 + r11)) : 0.f;
    float inv = rcpf(wave_sum(e0 + e1));
    ap0 = e0*inv; ap1 = e1*inv;

    // ctx raw reduces (20 independent DPP trees; inv folded at the end)
    float ws[20];
    #pragma unroll
    for (int u = 0; u < 20; u++) ws[u] = wave_sum(e0*er0[u] + e1*er1[u]);

    // z = ctx@Wx + h@Wh + b: packed v2, 2-way split chains (10-deep)
    v2 zx0 = (v2){0.f,0.f}, zx1 = (v2){0.f,0.f};
    v2 zh0 = dbp,            zh1 = (v2){0.f,0.f};
    #pragma unroll
    for (int u = 0; u < 20; u += 2){
      zx0 += ws[u]   *dwxp[u];
      zx1 += ws[u+1] *dwxp[u+1];
      zh0 += s_h[u]  *dwhp[u];
      zh1 += s_h[u+1]*dwhp[u+1];
    }
    v2 zzh = zh0 + zh1;
    v2 zzx = zx0 + zx1;
    float a0 = zzh.x + zzx.x*inv;
    float a1 = zzh.y + zzx.y*inv;
    float zf = BPERM(a0, lane+20);
    float zg = BPERM(a0, lane+40);
    // zo = a1: lane-local

    float hval = 0.f;
    if (lane < 20){
      c_dec = sigm(zf)*c_dec + sigm(a0)*ftanh(zg);
      hval  = sigm(a1)*ftanh(c_dec);
    }

    // state broadcast (feeds next step's q and zh)
    #pragma unroll
    for (int u = 0; u < 20; u++){ s_c[u] = RL(c_dec, u); s_h[u] = RL(hval, u); }

    // y output (dead-end, drains under next step's issue)
    float pv = wave_sum(hval*outw);
    if (lane == 0) g_out[(size_t)b*TDEC + t] = ftanh(pv + ob);
  }
}

extern "C" void kernel_launch(void* const* d_in, const int* in_sizes, int n_in,
                              void* d_out, int out_size, void* d_ws, size_t ws_size,
                              hipStream_t stream) {
  const float* g_in   = (const float*)d_in[0];
  const float* enc_Wx = (const float*)d_in[1];
  const float* enc_Wh = (const float*)d_in[2];
  const float* enc_b  = (const float*)d_in[3];
  const float* att_Wq = (const float*)d_in[4];
  const float* att_bq = (const float*)d_in[5];
  const float* att_Wm = (const float*)d_in[6];
  const float* att_bm = (const float*)d_in[7];
  const float* att_V  = (const float*)d_in[8];
  const float* att_bv = (const float*)d_in[9];
  const float* loc_Wc = (const float*)d_in[10];
  const float* loc_Wd = (const float*)d_in[11];
  const float* dec_Wx = (const float*)d_in[12];
  const float* dec_Wh = (const float*)d_in[13];
  const float* dec_b  = (const float*)d_in[14];
  const float* out_W  = (const float*)d_in[15];
  const float* out_b  = (const float*)d_in[16];
  float* g_out = (float*)d_out;

  hipLaunchKernelGGL(attn_rnn_kernel, dim3(NB), dim3(64), 0, stream,
                     g_in, enc_Wx, enc_Wh, enc_b, att_Wq, att_bq, att_Wm, att_bm,
                     att_V, att_bv, loc_Wc, loc_Wd, dec_Wx, dec_Wh, dec_b,
                     out_W, out_b, g_out);
}